// Round 10
// baseline (210.369 us; speedup 1.0000x reference)
//
#include <hip/hip_runtime.h>
#include <math.h>

#define CHANNEL 128
#define NEG_INF (-1e30f)
#define MSTRIDE 52   // M is [128][52] col-padded: M[c*52+r] = P2[r][c]

__device__ __forceinline__ float dot4(float4 a, float4 b) {
    return a.x * b.x + a.y * b.y + a.z * b.z + a.w * b.w;
}

// blocks [0,R): prep  M[c][r] = ((W W^T relw[r]^T)/16)[c],  rel_norm[r] = ||relw[r]||^2
// blocks [R,..): count degrees + per-edge rank (atomic return order)
__global__ void __launch_bounds__(256) prep_count_kernel(
    const float* __restrict__ relw, const float* __restrict__ W,
    const int* __restrict__ eidx, float* __restrict__ M,
    float* __restrict__ rel_norm, int* __restrict__ deg,
    unsigned short* __restrict__ rank, int E, int R)
{
    int b = blockIdx.x;
    if (b < R) {
        __shared__ float rw[CHANNEL];
        __shared__ float kr[CHANNEL];
        __shared__ float red[CHANNEL];
        int c = threadIdx.x;
        int j = b;
        if (c < CHANNEL) {
            float v = relw[j * CHANNEL + c];
            rw[c] = v;
            red[c] = v * v;
        }
        __syncthreads();
        for (int s = CHANNEL / 2; s > 0; s >>= 1) {
            if (c < s) red[c] += red[c + s];
            __syncthreads();
        }
        if (c == 0) rel_norm[j] = red[0];
        if (c < CHANNEL) {
            float acc = 0.f;
            for (int k = 0; k < CHANNEL; ++k) acc += rw[k] * W[k * CHANNEL + c];
            kr[c] = acc;
        }
        __syncthreads();
        if (c < CHANNEL) {
            float acc2 = 0.f;
            for (int cc = 0; cc < CHANNEL; ++cc) acc2 += W[c * CHANNEL + cc] * kr[cc];
            M[c * MSTRIDE + j] = acc2 * 0.0625f;   // transposed store
        }
    } else {
        int e = (b - R) * 256 + threadIdx.x;
        if (e < E) rank[e] = (unsigned short)atomicAdd(deg + eidx[e], 1);
    }
}

// blocks [0,nscan): hierarchical scan with last-block finisher
// blocks [nscan,..): S[h][r] = dot(ent[h], M[:,r]), 8 heads per wave
__global__ void __launch_bounds__(256) mid_kernel(
    const int* __restrict__ deg, int* __restrict__ raw, int* __restrict__ partial,
    int* __restrict__ counter, const float* __restrict__ ent,
    const float* __restrict__ M, float* __restrict__ S,
    int N, int R, int nscan)
{
    int b = blockIdx.x;
    int t = threadIdx.x;
    if (b < nscan) {
        __shared__ int sh[256];
        __shared__ int ticket_s;
        int i = b * 256 + t;
        int v = (i < N) ? deg[i] : 0;
        sh[t] = v;
        __syncthreads();
        for (int off = 1; off < 256; off <<= 1) {
            int u = (t >= off) ? sh[t - off] : 0;
            __syncthreads();
            sh[t] += u;
            __syncthreads();
        }
        if (i < N) raw[i] = sh[t] - v;
        if (t == 255) partial[b] = sh[255];
        __threadfence();
        if (t == 0) ticket_s = atomicAdd(counter, 1);
        __syncthreads();
        if (ticket_s == nscan - 1) {
            // last block: exclusive-scan partial[0..nscan)
            int pv = (t < nscan) ? partial[t] : 0;
            sh[t] = pv;
            __syncthreads();
            for (int off = 1; off < 256; off <<= 1) {
                int u = (t >= off) ? sh[t - off] : 0;
                __syncthreads();
                sh[t] += u;
                __syncthreads();
            }
            if (t < nscan) partial[t] = sh[t] - pv;
        }
    } else {
        // S computation: wave handles 8 heads, lane = relation slot
        int wid = (b - nscan) * 4 + (t >> 6);
        int h0 = wid * 8;
        if (h0 >= N) return;
        int r = t & 63;
        int rr = r < R ? r : 0;
        float acc0 = 0.f, acc1 = 0.f, acc2 = 0.f, acc3 = 0.f;
        float acc4 = 0.f, acc5 = 0.f, acc6 = 0.f, acc7 = 0.f;
        int hc[8];
#pragma unroll
        for (int i = 0; i < 8; ++i) {
            int h = h0 + i;
            hc[i] = h < N ? h : N - 1;
        }
        for (int c4 = 0; c4 < 32; ++c4) {
            int c = c4 * 4;
            float m0 = M[(c    ) * MSTRIDE + rr];
            float m1 = M[(c + 1) * MSTRIDE + rr];
            float m2 = M[(c + 2) * MSTRIDE + rr];
            float m3 = M[(c + 3) * MSTRIDE + rr];
            float4 hv;
#define SACC(i, A) \
            hv = ((const float4*)(ent + (size_t)hc[i] * CHANNEL))[c4]; \
            A += hv.x * m0 + hv.y * m1 + hv.z * m2 + hv.w * m3;
            SACC(0, acc0) SACC(1, acc1) SACC(2, acc2) SACC(3, acc3)
            SACC(4, acc4) SACC(5, acc5) SACC(6, acc6) SACC(7, acc7)
#undef SACC
        }
        if (r < R) {
            float accs[8] = {acc0, acc1, acc2, acc3, acc4, acc5, acc6, acc7};
#pragma unroll
            for (int i = 0; i < 8; ++i)
                if (h0 + i < N) S[(size_t)(h0 + i) * 50 + r] = accs[i];
        }
    }
}

// atomic-free placement: recs[start(h) + rank[e]] = { tail | type<<20, edge_id }
__global__ void place_kernel(const int* __restrict__ eidx, const int* __restrict__ etype,
                             const int* __restrict__ raw, const int* __restrict__ partial,
                             const unsigned short* __restrict__ rank,
                             int2* __restrict__ recs, int E) {
    int e = blockIdx.x * 256 + threadIdx.x;
    if (e >= E) return;
    int h = eidx[e];
    int t = eidx[E + e];
    int r = etype[e] - 1;
    int pos = raw[h] + partial[h >> 8] + (int)rank[e];
    recs[pos] = make_int2(t | (r << 20), e);
}

struct Row { float4 t0, t1; };

// one wave per head; 16 lanes/edge; only tail rows gathered (d2 = S lookup);
// depth-3 pipelined, guarded issues; 8 waves/EU target
__global__ void __launch_bounds__(256, 8) main_kernel(
        const float* __restrict__ ent, const float* __restrict__ S,
        const float* __restrict__ rel_norm, const int* __restrict__ raw,
        const int* __restrict__ partial, const int2* __restrict__ recs,
        float* __restrict__ out, int N, int E) {
    int wid = (int)((blockIdx.x * blockDim.x + threadIdx.x) >> 6);
    if (wid >= N) return;
    int lane = threadIdx.x & 63;

    int s0 = raw[wid] + partial[wid >> 8];
    int nxt = (wid + 1 < N) ? (raw[wid + 1] + partial[(wid + 1) >> 8]) : E;
    int deg_h = nxt - s0;
    if (deg_h == 0) return;

    const float4* hp = (const float4*)(ent + (size_t)wid * CHANNEL);
    const float* Sh = S + (size_t)wid * 50;

    if (deg_h <= 64) {
        int grp = lane >> 4;   // edge slot 0..3
        int sub = lane & 15;   // row sixteenth
        float4 h0 = hp[sub], h1 = hp[sub + 16];

        int lc = lane < deg_h ? lane : deg_h - 1;
        int2 rc = recs[s0 + lc];
        int iters = (deg_h + 3) >> 2;

        auto issue = [&](int g) -> Row {
            Row s;
            if (g < iters) {
                int e = 4 * g + grp;
                int ec = e < deg_h ? e : deg_h - 1;
                int rcx = __shfl(rc.x, ec);
                int tail = rcx & 0xFFFFF;
                const float4* tp = (const float4*)(ent + (size_t)tail * CHANNEL);
                s.t0 = tp[sub]; s.t1 = tp[sub + 16];
            } else {
                s.t0 = s.t1 = make_float4(0.f, 0.f, 0.f, 0.f);
            }
            return s;
        };

        float d1c = 0.f;
        auto compute = [&](int g, const Row& s) {
            float d1 = dot4(h0, s.t0) + dot4(h1, s.t1);
#pragma unroll
            for (int m = 1; m <= 8; m <<= 1) d1 += __shfl_xor(d1, m);
            int srcl = (lane & 3) * 16;
            float td1 = __shfl(d1, srcl);
            if ((lane >> 2) == g) d1c = td1;
        };

        Row A = issue(0);
        Row B = issue(1);
        int g = 0;
        for (;;) {
            Row C = issue(g + 2);
            compute(g, A);
            if (++g >= iters) break;
            A = issue(g + 2);
            compute(g, B);
            if (++g >= iters) break;
            B = issue(g + 2);
            compute(g, C);
            if (++g >= iters) break;
        }

        bool valid = lane < deg_h;
        int typc = rc.x >> 20;
        int eidc = rc.y;
        float d2c = Sh[typc];
        float m1 = valid ? d2c : NEG_INF;
#pragma unroll
        for (int m = 32; m; m >>= 1) m1 = fmaxf(m1, __shfl_xor(m1, m));
        float e1 = valid ? expf(d2c - m1) : 0.f;
        float s1 = e1;
#pragma unroll
        for (int m = 32; m; m >>= 1) s1 += __shfl_xor(s1, m);
        float rs = e1 / s1;
        float stv = d1c + rs * rs * rel_norm[typc];
        float m2 = valid ? stv : NEG_INF;
#pragma unroll
        for (int m = 32; m; m >>= 1) m2 = fmaxf(m2, __shfl_xor(m2, m));
        float e2 = valid ? expf(stv - m2) : 0.f;
        float s2 = e2;
#pragma unroll
        for (int m = 32; m; m >>= 1) s2 += __shfl_xor(s2, m);
        if (valid) out[eidc] = e2 / s2;
    } else {
        // slow path (deg > 64; ~never): multi-sweep, out[] as scratch
        int grp = lane >> 4;
        int sub = lane & 15;
        float4 H0 = hp[sub], H1 = hp[sub + 16];

        for (int k0 = 0; k0 < deg_h; k0 += 4) {
            int idx = k0 + grp;
            bool act = idx < deg_h;
            int j = s0 + (act ? idx : 0);
            int2 rc = recs[j];
            int tail = rc.x & 0xFFFFF;
            const float4* tp = (const float4*)(ent + (size_t)tail * CHANNEL);
            float d1 = dot4(H0, tp[sub]) + dot4(H1, tp[sub + 16]);
#pragma unroll
            for (int m = 1; m <= 8; m <<= 1) d1 += __shfl_xor(d1, m);
            if (act && sub == 0) out[rc.y] = d1;
        }
        float pm1 = NEG_INF;
        for (int k = lane; k < deg_h; k += 64)
            pm1 = fmaxf(pm1, Sh[recs[s0 + k].x >> 20]);
#pragma unroll
        for (int m = 32; m; m >>= 1) pm1 = fmaxf(pm1, __shfl_xor(pm1, m));
        float m1 = pm1;
        float s1p = 0.f;
        for (int k = lane; k < deg_h; k += 64)
            s1p += expf(Sh[recs[s0 + k].x >> 20] - m1);
#pragma unroll
        for (int m = 32; m; m >>= 1) s1p += __shfl_xor(s1p, m);
        float s1 = s1p;
        float pm2 = NEG_INF;
        for (int k = lane; k < deg_h; k += 64) {
            int2 rc = recs[s0 + k];
            int typ = rc.x >> 20;
            float e1 = expf(Sh[typ] - m1);
            float rsv = e1 / s1;
            float stv = out[rc.y] + rsv * rsv * rel_norm[typ];
            out[rc.y] = stv;
            pm2 = fmaxf(pm2, stv);
        }
#pragma unroll
        for (int m = 32; m; m >>= 1) pm2 = fmaxf(pm2, __shfl_xor(pm2, m));
        float m2 = pm2;
        float s2p = 0.f;
        for (int k = lane; k < deg_h; k += 64)
            s2p += expf(out[recs[s0 + k].y] - m2);
#pragma unroll
        for (int m = 32; m; m >>= 1) s2p += __shfl_xor(s2p, m);
        float s2 = s2p;
        for (int k = lane; k < deg_h; k += 64) {
            int eid = recs[s0 + k].y;
            out[eid] = expf(out[eid] - m2) / s2;
        }
    }
}

extern "C" void kernel_launch(void* const* d_in, const int* in_sizes, int n_in,
                              void* d_out, int out_size, void* d_ws, size_t ws_size,
                              hipStream_t stream) {
    const float* ent   = (const float*)d_in[0];
    const float* relw  = (const float*)d_in[2];
    const float* W     = (const float*)d_in[3];
    const int*   eidx  = (const int*)d_in[4];
    const int*   etype = (const int*)d_in[5];
    float* out = (float*)d_out;

    const int E = in_sizes[5];
    const int N = in_sizes[0] / CHANNEL;
    const int R = in_sizes[2] / CHANNEL;

    char* base = (char*)d_ws;
    auto alloc = [&](size_t bytes) {
        char* p = base;
        base += (bytes + 15) & ~(size_t)15;
        return p;
    };
    int*    deg      = (int*)alloc((size_t)N * 4);
    int*    counter  = (int*)alloc(16);              // adjacent to deg: one memset
    int*    raw      = (int*)alloc((size_t)N * 4);
    int*    partial  = (int*)alloc(1024 * 4);
    int2*   recs     = (int2*)alloc((size_t)E * 8);
    float*  M        = (float*)alloc((size_t)CHANNEL * MSTRIDE * 4);
    float*  rel_norm = (float*)alloc((size_t)R * 4);
    float*  S        = (float*)alloc((size_t)N * 50 * 4);
    unsigned short* rank = (unsigned short*)alloc((size_t)E * 2);

    // zero deg and counter in one memset (they are contiguous)
    hipMemsetAsync(deg, 0, (size_t)N * 4 + 16, stream);

    int ceblk = (E + 255) / 256;
    prep_count_kernel<<<R + ceblk, 256, 0, stream>>>(relw, W, eidx, M, rel_norm,
                                                     deg, rank, E, R);

    int nscan = (N + 255) / 256;          // 157 for N=40000; must be <= 256
    int nsb = (N + 31) / 32;              // S blocks: 32 heads per 256-thr block
    mid_kernel<<<nscan + nsb, 256, 0, stream>>>(deg, raw, partial, counter,
                                                ent, M, S, N, R, nscan);

    place_kernel<<<ceblk, 256, 0, stream>>>(eidx, etype, raw, partial, rank, recs, E);

    int bm = (N + 3) / 4;  // 4 waves per block, one wave per head
    main_kernel<<<bm, 256, 0, stream>>>(ent, S, rel_norm, raw, partial, recs, out, N, E);
}

// Round 11
// 138.312 us; speedup vs baseline: 1.5210x; 1.5210x over previous
//
#include <hip/hip_runtime.h>
#include <math.h>

#define CHANNEL 128
#define NEG_INF (-1e30f)

__device__ __forceinline__ float dot4(float4 a, float4 b) {
    return a.x * b.x + a.y * b.y + a.z * b.z + a.w * b.w;
}

// blocks [0,R): prep  P2[r] = (W W^T relw[r]^T)/16, rel_norm[r] = ||relw[r]||^2
// blocks [R,..): count degrees + per-edge rank (atomic return order)
__global__ void __launch_bounds__(256) prep_count_kernel(
    const float* __restrict__ relw, const float* __restrict__ W,
    const int* __restrict__ eidx, float* __restrict__ P2,
    float* __restrict__ rel_norm, int* __restrict__ deg,
    unsigned short* __restrict__ rank, int E, int R)
{
    int b = blockIdx.x;
    if (b < R) {
        __shared__ float rw[CHANNEL];
        __shared__ float kr[CHANNEL];
        __shared__ float red[CHANNEL];
        int c = threadIdx.x;
        int j = b;
        if (c < CHANNEL) {
            float v = relw[j * CHANNEL + c];
            rw[c] = v;
            red[c] = v * v;
        }
        __syncthreads();
        for (int s = CHANNEL / 2; s > 0; s >>= 1) {
            if (c < s) red[c] += red[c + s];
            __syncthreads();
        }
        if (c == 0) rel_norm[j] = red[0];
        if (c < CHANNEL) {
            float acc = 0.f;
            for (int k = 0; k < CHANNEL; ++k) acc += rw[k] * W[k * CHANNEL + c];
            kr[c] = acc;
        }
        __syncthreads();
        if (c < CHANNEL) {
            float acc2 = 0.f;
            for (int cc = 0; cc < CHANNEL; ++cc) acc2 += W[c * CHANNEL + cc] * kr[cc];
            P2[j * CHANNEL + c] = acc2 * 0.0625f;
        }
    } else {
        int e = (b - R) * 256 + threadIdx.x;
        if (e < E) rank[e] = (unsigned short)atomicAdd(deg + eidx[e], 1);
    }
}

// fused hierarchical scan: per-block local scan + last-block finisher over partials
__global__ void __launch_bounds__(256) scan_kernel(
    const int* __restrict__ deg, int* __restrict__ raw, int* __restrict__ partial,
    int* __restrict__ counter, int N, int nscan)
{
    __shared__ int sh[256];
    __shared__ int ticket_s;
    int b = blockIdx.x;
    int t = threadIdx.x;
    int i = b * 256 + t;
    int v = (i < N) ? deg[i] : 0;
    sh[t] = v;
    __syncthreads();
    for (int off = 1; off < 256; off <<= 1) {
        int u = (t >= off) ? sh[t - off] : 0;
        __syncthreads();
        sh[t] += u;
        __syncthreads();
    }
    if (i < N) raw[i] = sh[t] - v;
    if (t == 255) partial[b] = sh[255];
    __threadfence();
    if (t == 0) ticket_s = atomicAdd(counter, 1);
    __syncthreads();
    if (ticket_s == nscan - 1) {
        int pv = (t < nscan) ? partial[t] : 0;
        sh[t] = pv;
        __syncthreads();
        for (int off = 1; off < 256; off <<= 1) {
            int u = (t >= off) ? sh[t - off] : 0;
            __syncthreads();
            sh[t] += u;
            __syncthreads();
        }
        if (t < nscan) partial[t] = sh[t] - pv;
    }
}

// atomic-free placement: recs[start(h) + rank[e]] = { tail | type<<20, edge_id }
__global__ void __launch_bounds__(256) place_kernel(
    const int* __restrict__ eidx, const int* __restrict__ etype,
    const int* __restrict__ raw, const int* __restrict__ partial,
    const unsigned short* __restrict__ rank, int2* __restrict__ recs, int E)
{
    int e = blockIdx.x * 256 + threadIdx.x;
    if (e >= E) return;
    int h = eidx[e];
    int t = eidx[E + e];
    int r = etype[e] - 1;
    int pos = raw[h] + partial[h >> 8] + (int)rank[e];
    recs[pos] = make_int2(t | (r << 20), e);
}

struct Row { float4 t0, t1, r0, r1; };

// one wave per head; 16 lanes/edge; inline d1+d2 dots; depth-3 guarded pipeline
__global__ void __launch_bounds__(256, 4) main_kernel(
        const float* __restrict__ ent, const float* __restrict__ P2,
        const float* __restrict__ rel_norm, const int* __restrict__ raw,
        const int* __restrict__ partial, const int2* __restrict__ recs,
        float2* __restrict__ sc, float* __restrict__ out, int N, int E) {
    int wid = (int)((blockIdx.x * blockDim.x + threadIdx.x) >> 6);
    if (wid >= N) return;
    int lane = threadIdx.x & 63;
    int grp = lane >> 4;
    int sub = lane & 15;

    int s0 = raw[wid] + partial[wid >> 8];
    int nxt = (wid + 1 < N) ? (raw[wid + 1] + partial[(wid + 1) >> 8]) : E;
    int deg_h = nxt - s0;
    if (deg_h == 0) return;

    const float4* hp = (const float4*)(ent + (size_t)wid * CHANNEL);
    float4 h0 = hp[sub], h1 = hp[sub + 16];

    if (deg_h <= 64) {
        // lane l owns edge l (clamped): coalesced 8B rec load
        int lc = lane < deg_h ? lane : deg_h - 1;
        int2 rc = recs[s0 + lc];
        int iters = (deg_h + 3) >> 2;

        auto issue = [&](int g) -> Row {
            Row s;
            if (g < iters) {   // uniform guard: no issues past the end
                int e = 4 * g + grp;
                int ec = e < deg_h ? e : deg_h - 1;
                int rcx = __shfl(rc.x, ec);
                int tail = rcx & 0xFFFFF;
                int typ = rcx >> 20;
                const float4* tp = (const float4*)(ent + (size_t)tail * CHANNEL);
                const float4* rp = (const float4*)(P2 + typ * CHANNEL);
                s.t0 = tp[sub]; s.t1 = tp[sub + 16];
                s.r0 = rp[sub]; s.r1 = rp[sub + 16];
            } else {
                s.t0 = s.t1 = s.r0 = s.r1 = make_float4(0.f, 0.f, 0.f, 0.f);
            }
            return s;
        };

        float d1c = 0.f, d2c = 0.f;
        auto compute = [&](int g, const Row& s) {
            float d1 = dot4(h0, s.t0) + dot4(h1, s.t1);
            float d2 = dot4(h0, s.r0) + dot4(h1, s.r1);
#pragma unroll
            for (int m = 1; m <= 8; m <<= 1) {
                d1 += __shfl_xor(d1, m);
                d2 += __shfl_xor(d2, m);
            }
            int srcl = (lane & 3) * 16;
            float td1 = __shfl(d1, srcl);
            float td2 = __shfl(d2, srcl);
            if ((lane >> 2) == g) { d1c = td1; d2c = td2; }
        };

        Row A = issue(0);
        Row B = issue(1);
        int g = 0;
        for (;;) {
            Row C = issue(g + 2);
            compute(g, A);
            if (++g >= iters) break;
            A = issue(g + 2);
            compute(g, B);
            if (++g >= iters) break;
            B = issue(g + 2);
            compute(g, C);
            if (++g >= iters) break;
        }

        bool valid = lane < deg_h;
        int typc = rc.x >> 20;
        int eidc = rc.y;
        // softmax 1 over d2
        float m1 = valid ? d2c : NEG_INF;
#pragma unroll
        for (int m = 32; m; m >>= 1) m1 = fmaxf(m1, __shfl_xor(m1, m));
        float e1 = valid ? expf(d2c - m1) : 0.f;
        float s1 = e1;
#pragma unroll
        for (int m = 32; m; m >>= 1) s1 += __shfl_xor(s1, m);
        float rs = e1 / s1;
        // trip score + softmax 2
        float stv = d1c + rs * rs * rel_norm[typc];
        float m2 = valid ? stv : NEG_INF;
#pragma unroll
        for (int m = 32; m; m >>= 1) m2 = fmaxf(m2, __shfl_xor(m2, m));
        float e2 = valid ? expf(stv - m2) : 0.f;
        float s2 = e2;
#pragma unroll
        for (int m = 32; m; m >>= 1) s2 += __shfl_xor(s2, m);
        if (valid) out[eidc] = e2 / s2;
    } else {
        // slow path (deg > 64; ~never for this distribution): multi-sweep via sc
        float pm1 = NEG_INF;
        for (int k0 = 0; k0 < deg_h; k0 += 4) {
            int idx = k0 + grp;
            bool act = idx < deg_h;
            int j = s0 + (act ? idx : 0);
            int2 rc = recs[j];
            float d1 = 0.f, d2 = 0.f;
            if (act) {
                int tail = rc.x & 0xFFFFF;
                int typ = rc.x >> 20;
                const float4* tp = (const float4*)(ent + (size_t)tail * CHANNEL);
                const float4* rp = (const float4*)(P2 + typ * CHANNEL);
                d1 = dot4(h0, tp[sub]) + dot4(h1, tp[sub + 16]);
                d2 = dot4(h0, rp[sub]) + dot4(h1, rp[sub + 16]);
            }
#pragma unroll
            for (int m = 1; m <= 8; m <<= 1) {
                d1 += __shfl_xor(d1, m);
                d2 += __shfl_xor(d2, m);
            }
            if (act) {
                if (sub == 0) sc[j] = make_float2(d1, d2);
                pm1 = fmaxf(pm1, d2);
            }
        }
        pm1 = fmaxf(pm1, __shfl_xor(pm1, 16));
        pm1 = fmaxf(pm1, __shfl_xor(pm1, 32));
        float m1 = pm1;

        float s1 = 0.f;
        for (int k = lane; k < deg_h; k += 64) s1 += expf(sc[s0 + k].y - m1);
#pragma unroll
        for (int m = 32; m; m >>= 1) s1 += __shfl_xor(s1, m);

        float pm2 = NEG_INF;
        for (int k = lane; k < deg_h; k += 64) {
            float2 v = sc[s0 + k];
            int typ = recs[s0 + k].x >> 20;
            float e1 = expf(v.y - m1);
            float rsv = e1 / s1;
            float stv = v.x + rsv * rsv * rel_norm[typ];
            sc[s0 + k].x = stv;
            pm2 = fmaxf(pm2, stv);
        }
#pragma unroll
        for (int m = 32; m; m >>= 1) pm2 = fmaxf(pm2, __shfl_xor(pm2, m));
        float m2 = pm2;

        float s2 = 0.f;
        for (int k = lane; k < deg_h; k += 64) {
            float e2 = expf(sc[s0 + k].x - m2);
            sc[s0 + k].y = e2;
            s2 += e2;
        }
#pragma unroll
        for (int m = 32; m; m >>= 1) s2 += __shfl_xor(s2, m);
        float inv = 1.f / s2;

        for (int k = lane; k < deg_h; k += 64)
            out[recs[s0 + k].y] = sc[s0 + k].y * inv;
    }
}

extern "C" void kernel_launch(void* const* d_in, const int* in_sizes, int n_in,
                              void* d_out, int out_size, void* d_ws, size_t ws_size,
                              hipStream_t stream) {
    const float* ent   = (const float*)d_in[0];
    const float* relw  = (const float*)d_in[2];
    const float* W     = (const float*)d_in[3];
    const int*   eidx  = (const int*)d_in[4];
    const int*   etype = (const int*)d_in[5];
    float* out = (float*)d_out;

    const int E = in_sizes[5];
    const int N = in_sizes[0] / CHANNEL;
    const int R = in_sizes[2] / CHANNEL;

    char* base = (char*)d_ws;
    auto alloc = [&](size_t bytes) {
        char* p = base;
        base += (bytes + 15) & ~(size_t)15;
        return p;
    };
    int*    deg      = (int*)alloc((size_t)N * 4);
    int*    counter  = (int*)alloc(16);              // adjacent to deg: one memset
    int*    raw      = (int*)alloc((size_t)N * 4);
    int*    partial  = (int*)alloc(1024 * 4);
    int2*   recs     = (int2*)alloc((size_t)E * 8);
    float*  P2       = (float*)alloc((size_t)R * CHANNEL * 4);
    float*  rel_norm = (float*)alloc((size_t)R * 4);
    unsigned short* rank = (unsigned short*)alloc((size_t)E * 2);
    float2* sc       = (float2*)alloc((size_t)E * 8);

    hipMemsetAsync(deg, 0, (size_t)N * 4 + 16, stream);

    int ceblk = (E + 255) / 256;
    prep_count_kernel<<<R + ceblk, 256, 0, stream>>>(relw, W, eidx, P2, rel_norm,
                                                     deg, rank, E, R);

    int nscan = (N + 255) / 256;   // 157 for N=40000; must be <= 256
    scan_kernel<<<nscan, 256, 0, stream>>>(deg, raw, partial, counter, N, nscan);

    place_kernel<<<ceblk, 256, 0, stream>>>(eidx, etype, raw, partial, rank, recs, E);

    int bm = (N + 3) / 4;  // 4 waves per block, one wave per head
    main_kernel<<<bm, 256, 0, stream>>>(ent, P2, rel_norm, raw, partial, recs, sc, out, N, E);
}

// Round 12
// 113.044 us; speedup vs baseline: 1.8609x; 1.2235x over previous
//
#include <hip/hip_runtime.h>
#include <math.h>

#define CHANNEL 128
#define NEG_INF (-1e30f)

__device__ __forceinline__ float dot4(float4 a, float4 b) {
    return a.x * b.x + a.y * b.y + a.z * b.z + a.w * b.w;
}

// blocks [0,R): prep  P2[r] = (W W^T relw[r]^T)/16, rel_norm[r] = ||relw[r]||^2
// blocks [R,..): count degrees + per-edge rank, 4 edges/thread (int4 loads)
__global__ void __launch_bounds__(256) prep_count_kernel(
    const float* __restrict__ relw, const float* __restrict__ W,
    const int* __restrict__ eidx, float* __restrict__ P2,
    float* __restrict__ rel_norm, int* __restrict__ deg,
    unsigned short* __restrict__ rank, int E, int R)
{
    int b = blockIdx.x;
    if (b < R) {
        __shared__ float rw[CHANNEL];
        __shared__ float kr[CHANNEL];
        __shared__ float red[CHANNEL];
        int c = threadIdx.x;
        int j = b;
        if (c < CHANNEL) {
            float v = relw[j * CHANNEL + c];
            rw[c] = v;
            red[c] = v * v;
        }
        __syncthreads();
        for (int s = CHANNEL / 2; s > 0; s >>= 1) {
            if (c < s) red[c] += red[c + s];
            __syncthreads();
        }
        if (c == 0) rel_norm[j] = red[0];
        if (c < CHANNEL) {
            float acc = 0.f;
            for (int k = 0; k < CHANNEL; ++k) acc += rw[k] * W[k * CHANNEL + c];
            kr[c] = acc;
        }
        __syncthreads();
        if (c < CHANNEL) {
            float acc2 = 0.f;
            for (int cc = 0; cc < CHANNEL; ++cc) acc2 += W[c * CHANNEL + cc] * kr[cc];
            P2[j * CHANNEL + c] = acc2 * 0.0625f;
        }
    } else {
        int e4 = ((b - R) * 256 + threadIdx.x) * 4;
        if (e4 + 3 < E) {
            int4 h4 = *(const int4*)(eidx + e4);
            ushort4 rk;
            rk.x = (unsigned short)atomicAdd(deg + h4.x, 1);
            rk.y = (unsigned short)atomicAdd(deg + h4.y, 1);
            rk.z = (unsigned short)atomicAdd(deg + h4.z, 1);
            rk.w = (unsigned short)atomicAdd(deg + h4.w, 1);
            *(ushort4*)(rank + e4) = rk;
        } else {
            for (int e = e4; e < E; ++e)
                rank[e] = (unsigned short)atomicAdd(deg + eidx[e], 1);
        }
    }
}

// fused hierarchical scan: per-block local scan + last-block finisher over partials
__global__ void __launch_bounds__(256) scan_kernel(
    const int* __restrict__ deg, int* __restrict__ raw, int* __restrict__ partial,
    int* __restrict__ counter, int N, int nscan)
{
    __shared__ int sh[256];
    __shared__ int ticket_s;
    int b = blockIdx.x;
    int t = threadIdx.x;
    int i = b * 256 + t;
    int v = (i < N) ? deg[i] : 0;
    sh[t] = v;
    __syncthreads();
    for (int off = 1; off < 256; off <<= 1) {
        int u = (t >= off) ? sh[t - off] : 0;
        __syncthreads();
        sh[t] += u;
        __syncthreads();
    }
    if (i < N) raw[i] = sh[t] - v;
    if (t == 255) partial[b] = sh[255];
    __threadfence();
    if (t == 0) ticket_s = atomicAdd(counter, 1);
    __syncthreads();
    if (ticket_s == nscan - 1) {
        int pv = (t < nscan) ? partial[t] : 0;
        sh[t] = pv;
        __syncthreads();
        for (int off = 1; off < 256; off <<= 1) {
            int u = (t >= off) ? sh[t - off] : 0;
            __syncthreads();
            sh[t] += u;
            __syncthreads();
        }
        if (t < nscan) partial[t] = sh[t] - pv;
    }
}

// atomic-free placement, 4 edges/thread:
// recs[start(h) + rank[e]] = { tail | type<<20, edge_id }
__global__ void __launch_bounds__(256) place_kernel(
    const int* __restrict__ eidx, const int* __restrict__ etype,
    const int* __restrict__ raw, const int* __restrict__ partial,
    const unsigned short* __restrict__ rank, int2* __restrict__ recs, int E)
{
    int e4 = (blockIdx.x * 256 + threadIdx.x) * 4;
    if (e4 + 3 < E) {
        int4 h4 = *(const int4*)(eidx + e4);
        int4 t4 = *(const int4*)(eidx + E + e4);
        int4 r4 = *(const int4*)(etype + e4);
        ushort4 k4 = *(const ushort4*)(rank + e4);
        recs[raw[h4.x] + partial[h4.x >> 8] + k4.x] = make_int2(t4.x | ((r4.x - 1) << 20), e4);
        recs[raw[h4.y] + partial[h4.y >> 8] + k4.y] = make_int2(t4.y | ((r4.y - 1) << 20), e4 + 1);
        recs[raw[h4.z] + partial[h4.z >> 8] + k4.z] = make_int2(t4.z | ((r4.z - 1) << 20), e4 + 2);
        recs[raw[h4.w] + partial[h4.w >> 8] + k4.w] = make_int2(t4.w | ((r4.w - 1) << 20), e4 + 3);
    } else {
        for (int e = e4; e < E; ++e) {
            int h = eidx[e];
            int pos = raw[h] + partial[h >> 8] + (int)rank[e];
            recs[pos] = make_int2(eidx[E + e] | ((etype[e] - 1) << 20), e);
        }
    }
}

struct Row { float4 t0, t1, r0, r1; };

// one wave per head; 16 lanes/edge; depth-2 pipeline, clamped issue (R6-proven)
__global__ void __launch_bounds__(256, 4) main_kernel(
        const float* __restrict__ ent, const float* __restrict__ P2,
        const float* __restrict__ rel_norm, const int* __restrict__ raw,
        const int* __restrict__ partial, const int2* __restrict__ recs,
        float2* __restrict__ sc, float* __restrict__ out, int N, int E) {
    int wid = (int)((blockIdx.x * blockDim.x + threadIdx.x) >> 6);
    if (wid >= N) return;
    int lane = threadIdx.x & 63;
    int grp = lane >> 4;
    int sub = lane & 15;

    int s0 = raw[wid] + partial[wid >> 8];
    int nxt = (wid + 1 < N) ? (raw[wid + 1] + partial[(wid + 1) >> 8]) : E;
    int deg_h = nxt - s0;
    if (deg_h == 0) return;

    const float4* hp = (const float4*)(ent + (size_t)wid * CHANNEL);
    float4 h0 = hp[sub], h1 = hp[sub + 16];

    if (deg_h <= 64) {
        // lane l owns edge l (clamped): one coalesced 8B load for the rec
        int lc = lane < deg_h ? lane : deg_h - 1;
        int2 rc = recs[s0 + lc];
        int iters = (deg_h + 3) >> 2;

        auto issue = [&](int g) -> Row {
            Row s;
            int e = 4 * g + grp;
            int ec = e < deg_h ? e : deg_h - 1;
            int rcx = __shfl(rc.x, ec);
            int tail = rcx & 0xFFFFF;
            int typ = rcx >> 20;
            const float4* tp = (const float4*)(ent + (size_t)tail * CHANNEL);
            const float4* rp = (const float4*)(P2 + typ * CHANNEL);
            s.t0 = tp[sub]; s.t1 = tp[sub + 16];
            s.r0 = rp[sub]; s.r1 = rp[sub + 16];
            return s;
        };

        float d1c = 0.f, d2c = 0.f;
        auto compute = [&](int g, const Row& s) {
            float d1 = dot4(h0, s.t0) + dot4(h1, s.t1);
            float d2 = dot4(h0, s.r0) + dot4(h1, s.r1);
#pragma unroll
            for (int m = 1; m <= 8; m <<= 1) {
                d1 += __shfl_xor(d1, m);
                d2 += __shfl_xor(d2, m);
            }
            int srcl = (lane & 3) * 16;
            float td1 = __shfl(d1, srcl);
            float td2 = __shfl(d2, srcl);
            if ((lane >> 2) == g) { d1c = td1; d2c = td2; }
        };

        Row A = issue(0);
        int g = 0;
        while (g < iters) {
            Row B = issue(g + 1);   // may clamp past end: harmless, L1-absorbed
            compute(g, A);
            ++g;
            if (g >= iters) break;
            A = issue(g + 1);
            compute(g, B);
            ++g;
        }

        bool valid = lane < deg_h;
        int typc = rc.x >> 20;
        int eidc = rc.y;
        // softmax 1 over d2
        float m1 = valid ? d2c : NEG_INF;
#pragma unroll
        for (int m = 32; m; m >>= 1) m1 = fmaxf(m1, __shfl_xor(m1, m));
        float e1 = valid ? expf(d2c - m1) : 0.f;
        float s1 = e1;
#pragma unroll
        for (int m = 32; m; m >>= 1) s1 += __shfl_xor(s1, m);
        float rs = e1 / s1;
        // trip score + softmax 2
        float stv = d1c + rs * rs * rel_norm[typc];
        float m2 = valid ? stv : NEG_INF;
#pragma unroll
        for (int m = 32; m; m >>= 1) m2 = fmaxf(m2, __shfl_xor(m2, m));
        float e2 = valid ? expf(stv - m2) : 0.f;
        float s2 = e2;
#pragma unroll
        for (int m = 32; m; m >>= 1) s2 += __shfl_xor(s2, m);
        if (valid) out[eidc] = e2 / s2;
    } else {
        // slow path (deg > 64; ~never for this distribution): multi-sweep via sc
        float pm1 = NEG_INF;
        for (int k0 = 0; k0 < deg_h; k0 += 4) {
            int idx = k0 + grp;
            bool act = idx < deg_h;
            int j = s0 + (act ? idx : 0);
            int2 rc = recs[j];
            float d1 = 0.f, d2 = 0.f;
            if (act) {
                int tail = rc.x & 0xFFFFF;
                int typ = rc.x >> 20;
                const float4* tp = (const float4*)(ent + (size_t)tail * CHANNEL);
                const float4* rp = (const float4*)(P2 + typ * CHANNEL);
                d1 = dot4(h0, tp[sub]) + dot4(h1, tp[sub + 16]);
                d2 = dot4(h0, rp[sub]) + dot4(h1, rp[sub + 16]);
            }
#pragma unroll
            for (int m = 1; m <= 8; m <<= 1) {
                d1 += __shfl_xor(d1, m);
                d2 += __shfl_xor(d2, m);
            }
            if (act) {
                if (sub == 0) sc[j] = make_float2(d1, d2);
                pm1 = fmaxf(pm1, d2);
            }
        }
        pm1 = fmaxf(pm1, __shfl_xor(pm1, 16));
        pm1 = fmaxf(pm1, __shfl_xor(pm1, 32));
        float m1 = pm1;

        float s1 = 0.f;
        for (int k = lane; k < deg_h; k += 64) s1 += expf(sc[s0 + k].y - m1);
#pragma unroll
        for (int m = 32; m; m >>= 1) s1 += __shfl_xor(s1, m);

        float pm2 = NEG_INF;
        for (int k = lane; k < deg_h; k += 64) {
            float2 v = sc[s0 + k];
            int typ = recs[s0 + k].x >> 20;
            float e1 = expf(v.y - m1);
            float rsv = e1 / s1;
            float stv = v.x + rsv * rsv * rel_norm[typ];
            sc[s0 + k].x = stv;
            pm2 = fmaxf(pm2, stv);
        }
#pragma unroll
        for (int m = 32; m; m >>= 1) pm2 = fmaxf(pm2, __shfl_xor(pm2, m));
        float m2 = pm2;

        float s2 = 0.f;
        for (int k = lane; k < deg_h; k += 64) {
            float e2 = expf(sc[s0 + k].x - m2);
            sc[s0 + k].y = e2;
            s2 += e2;
        }
#pragma unroll
        for (int m = 32; m; m >>= 1) s2 += __shfl_xor(s2, m);
        float inv = 1.f / s2;

        for (int k = lane; k < deg_h; k += 64)
            out[recs[s0 + k].y] = sc[s0 + k].y * inv;
    }
}

extern "C" void kernel_launch(void* const* d_in, const int* in_sizes, int n_in,
                              void* d_out, int out_size, void* d_ws, size_t ws_size,
                              hipStream_t stream) {
    const float* ent   = (const float*)d_in[0];
    const float* relw  = (const float*)d_in[2];
    const float* W     = (const float*)d_in[3];
    const int*   eidx  = (const int*)d_in[4];
    const int*   etype = (const int*)d_in[5];
    float* out = (float*)d_out;

    const int E = in_sizes[5];
    const int N = in_sizes[0] / CHANNEL;
    const int R = in_sizes[2] / CHANNEL;

    char* base = (char*)d_ws;
    auto alloc = [&](size_t bytes) {
        char* p = base;
        base += (bytes + 15) & ~(size_t)15;
        return p;
    };
    int*    deg      = (int*)alloc((size_t)N * 4);
    int*    counter  = (int*)alloc(16);              // adjacent to deg: one memset
    int*    raw      = (int*)alloc((size_t)N * 4);
    int*    partial  = (int*)alloc(1024 * 4);
    int2*   recs     = (int2*)alloc((size_t)E * 8);
    float*  P2       = (float*)alloc((size_t)R * CHANNEL * 4);
    float*  rel_norm = (float*)alloc((size_t)R * 4);
    unsigned short* rank = (unsigned short*)alloc((size_t)E * 2);
    float2* sc       = (float2*)alloc((size_t)E * 8);

    hipMemsetAsync(deg, 0, (size_t)N * 4 + 16, stream);

    int ceblk4 = (E / 4 + 255) / 256;   // 4 edges per thread
    prep_count_kernel<<<R + ceblk4, 256, 0, stream>>>(relw, W, eidx, P2, rel_norm,
                                                      deg, rank, E, R);

    int nscan = (N + 255) / 256;   // 157 for N=40000; must be <= 256
    scan_kernel<<<nscan, 256, 0, stream>>>(deg, raw, partial, counter, N, nscan);

    place_kernel<<<ceblk4, 256, 0, stream>>>(eidx, etype, raw, partial, rank, recs, E);

    int bm = (N + 3) / 4;  // 4 waves per block, one wave per head
    main_kernel<<<bm, 256, 0, stream>>>(ent, P2, rel_norm, raw, partial, recs, sc, out, N, E);
}